// Round 13
// baseline (1593.092 us; speedup 1.0000x reference)
//
#include <hip/hip_runtime.h>
#include <hip/hip_bf16.h>

// Problem constants
#define BB 16
#define SS 128
#define DD 128
#define EE 64
#define TT 128
#define NN (BB*SS)      // 2048 tokens
#define KSPLIT 16       // K split for the big GEMM (d-chunks of 8)
#define AMP 16          // ROUND-12 DIAGNOSTIC: per-kernel internal amplification (idempotent)

typedef __attribute__((ext_vector_type(8))) short short8;
typedef __attribute__((ext_vector_type(4))) float f32x4;
typedef __attribute__((ext_vector_type(4))) unsigned int u32x4;

__device__ inline unsigned pkbf16(float a, float b) {
    unsigned r;
    asm volatile("v_cvt_pk_bf16_f32 %0, %1, %2" : "=v"(r) : "v"(a), "v"(b));
    return r;
}
__device__ inline float bflo(unsigned u) { return __builtin_bit_cast(float, (unsigned)(u << 16)); }
__device__ inline float bfhi(unsigned u) { return __builtin_bit_cast(float, (unsigned)(u & 0xffff0000u)); }
// opaque zero: defeats invariant-load hoisting across AMP iterations
__device__ inline int opaque_zero() { int z = 0; asm volatile("" : "+v"(z)); return z; }

#define LDS_SWZ(row, bcol) ((row) * 256 + ((bcol) ^ (((row) & 7) << 4)))

// ---------------- prep1: g1 (512 blk) + w2b (1024) + basics (1) ----------------
__global__ __launch_bounds__(256) void k_prep1(const float* __restrict__ W1,
                                               const float* __restrict__ dep_table,
                                               const float* __restrict__ W2,
                                               const float* __restrict__ b2,
                                               const float* __restrict__ wr,
                                               const float* __restrict__ br,
                                               __hip_bfloat16* __restrict__ G1,
                                               __hip_bfloat16* __restrict__ W2b,
                                               float* __restrict__ basics) {
    int bid = blockIdx.x;
    int tid = threadIdx.x;
#pragma unroll 1
    for (int it = 0; it < AMP; it++) {
        int z = opaque_zero();
        if (bid < 512) {
            int bx = bid & 63, by = bid >> 6;
            int td = bx * 256 + tid;  // t*128 + d
            int v0 = by * 8;          // 8 v per block
            const float* w1row = W1 + (size_t)td * 64 + z;
            float acc[8] = {};
#pragma unroll
            for (int e0 = 0; e0 < 64; e0 += 8) {
                f32x4 wa = *(const f32x4*)(w1row + e0);
                f32x4 wb = *(const f32x4*)(w1row + e0 + 4);
#pragma unroll
                for (int v = 0; v < 8; v++) {
                    const float* dr = dep_table + (v0 + v) * 64 + e0;  // wave-uniform -> s_load
                    acc[v] += wa[0] * dr[0] + wa[1] * dr[1] + wa[2] * dr[2] + wa[3] * dr[3]
                            + wb[0] * dr[4] + wb[1] * dr[5] + wb[2] * dr[6] + wb[3] * dr[7];
                }
            }
#pragma unroll
            for (int v = 0; v < 8; v++)
                G1[(size_t)(v0 + v) * (TT * DD) + td] = __float2bfloat16(acc[v]);
        } else if (bid < 1536) {
            int cid = (bid - 512) * 256 + tid;  // 262144 chunks of 16B
            int d = cid >> 11;
            int rem = cid & 2047;
            int p = rem >> 4;
            int sp = rem & 15;
            int h = sp >> 3, s = sp & 7;
            int t0 = h * 64 + ((s ^ (p & 7))) * 8;
            const float* src = W2 + ((size_t)p * 128 + d) * 128 + t0 + z;  // W2[p][d][t]
            f32x4 a = *(const f32x4*)(src);
            f32x4 b = *(const f32x4*)(src + 4);
            u32x4 o;
            o[0] = pkbf16(a[0], a[1]);
            o[1] = pkbf16(a[2], a[3]);
            o[2] = pkbf16(b[0], b[1]);
            o[3] = pkbf16(b[2], b[3]);
            *(u32x4*)((char*)W2b + (size_t)cid * 16) = o;
        } else {
            __shared__ float red[128];
            int t = tid;
            if (t < 128) red[t] = wr[t + z];
            __syncthreads();
            for (int s = 64; s > 0; s >>= 1) {
                if (t < s) red[t] += red[t + s];
                __syncthreads();
            }
            if (t < 128) {
                float swr = red[0];
                float cbg = tanhf(b2[t]);
                basics[t] = cbg;                     // c_bg[p]
                basics[128 + t] = swr * cbg + br[0]; // base[p]
            }
            __syncthreads();
        }
    }
}

// ---------------- prep2: gather tok + fused depth-0 tde ----------------
__global__ __launch_bounds__(256) void k_prep2(const float* __restrict__ token_table,
                                               const int* __restrict__ tokens,
                                               const int* __restrict__ dep_types,
                                               const float* __restrict__ b1,
                                               const __hip_bfloat16* __restrict__ G1,
                                               float* __restrict__ tok,
                                               float* __restrict__ tde) {
    __shared__ float rows[2][128];
    int tid = threadIdx.x;
    int gid = blockIdx.x * 256 + tid;
    int n = gid >> 7, t = tid & 127, half = tid >> 7;
#pragma unroll 1
    for (int it = 0; it < AMP; it++) {
        int z = opaque_zero();
        float val = token_table[(size_t)tokens[n] * 128 + t + z];
        tok[gid] = val;
        rows[half][t] = val;
        __syncthreads();
        int v = dep_types[n];
        const unsigned* g = (const unsigned*)(G1 + (size_t)v * (TT * DD) + t * 128) + z;
        const float* row = rows[half];
        float acc = b1[t];
#pragma unroll
        for (int i = 0; i < 16; i++) {
            u32x4 w = *(const u32x4*)(g + i * 4);
            acc += row[i * 8 + 0] * bflo(w[0]) + row[i * 8 + 1] * bfhi(w[0]);
            acc += row[i * 8 + 2] * bflo(w[1]) + row[i * 8 + 3] * bfhi(w[1]);
            acc += row[i * 8 + 4] * bflo(w[2]) + row[i * 8 + 5] * bfhi(w[2]);
            acc += row[i * 8 + 6] * bflo(w[3]) + row[i * 8 + 7] * bfhi(w[3]);
        }
        tde[(size_t)n * 128 + t] = tanhf(acc);
        __syncthreads();
    }
}

// ---------------- big GEMM ----------------
__global__ __launch_bounds__(256) void k_gemm(const float* __restrict__ tok,
                                              const float* __restrict__ tde,
                                              const __hip_bfloat16* __restrict__ W2b,
                                              float* __restrict__ part) {
    __shared__ char As[16384];  // A tile [n=64][k=128t] bf16, swizzled
    __shared__ char Bs[32768];  // B tile [p=128][k=128t] bf16, swizzled
    int nb = blockIdx.x, ks = blockIdx.y;
    int tid = threadIdx.x;
    int lane = tid & 63, w = tid >> 6;
    int wm = w >> 1, wp = w & 1;
    int n0 = nb * 64, d0 = ks * 8;
    int lrow = lane & 15, lk = lane >> 4;
    int r = tid >> 2, q = tid & 3;
#pragma unroll 1
    for (int it = 0; it < AMP; it++) {
        int z = opaque_zero();
        f32x4 acc[2][4] = {};
        for (int dd = 0; dd < 8; dd++) {
            int d = d0 + dd;
            const char* bsrc = (const char*)W2b + (size_t)d * 32768 + z;
#pragma unroll
            for (int i = 0; i < 8; i++) {
                int off = (i * 256 + tid) * 16;
                *(u32x4*)(Bs + off) = *(const u32x4*)(bsrc + off);
            }
            float tokv = tok[(size_t)(n0 + r) * 128 + d + z];
            const float* trow = tde + (size_t)(n0 + r) * 128 + q * 32 + z;
#pragma unroll
            for (int s = 0; s < 4; s++) {
                f32x4 x = *(const f32x4*)(trow + s * 8);
                f32x4 y = *(const f32x4*)(trow + s * 8 + 4);
                u32x4 val;
                val[0] = pkbf16(x[0] * tokv, x[1] * tokv);
                val[1] = pkbf16(x[2] * tokv, x[3] * tokv);
                val[2] = pkbf16(y[0] * tokv, y[1] * tokv);
                val[3] = pkbf16(y[2] * tokv, y[3] * tokv);
                int bcol = q * 64 + s * 16;
                *(u32x4*)(As + LDS_SWZ(r, bcol)) = val;
            }
            __syncthreads();
#pragma unroll
            for (int kk = 0; kk < 4; kk++) {
                short8 aF[2], bF[4];
#pragma unroll
                for (int mi = 0; mi < 2; mi++) {
                    int row = wm * 32 + mi * 16 + lrow;
                    aF[mi] = *(const short8*)(As + LDS_SWZ(row, kk * 64 + lk * 16));
                }
#pragma unroll
                for (int pj = 0; pj < 4; pj++) {
                    int row = wp * 64 + pj * 16 + lrow;
                    bF[pj] = *(const short8*)(Bs + LDS_SWZ(row, kk * 64 + lk * 16));
                }
#pragma unroll
                for (int mi = 0; mi < 2; mi++)
#pragma unroll
                    for (int pj = 0; pj < 4; pj++)
                        acc[mi][pj] = __builtin_amdgcn_mfma_f32_16x16x32_bf16(
                            aF[mi], bF[pj], acc[mi][pj], 0, 0, 0);
            }
            __syncthreads();
        }
        float* pout = part + (size_t)ks * NN * 128;
#pragma unroll
        for (int mi = 0; mi < 2; mi++)
#pragma unroll
            for (int pj = 0; pj < 4; pj++)
#pragma unroll
                for (int rr = 0; rr < 4; rr++) {
                    int row = wm * 32 + mi * 16 + (lane >> 4) * 4 + rr;
                    int col = wp * 64 + pj * 16 + (lane & 15);
                    pout[(size_t)(n0 + row) * 128 + col] = acc[mi][pj][rr];
                }
    }
}

// ---------------- e2a (depth 0): fused e1 + scatter + fused tde for depth 1 ----------------
__global__ void k_e2a(const float* __restrict__ part, const int* __restrict__ heads,
                      const float* __restrict__ basics, const float* __restrict__ wr,
                      const float* __restrict__ b2, const int* __restrict__ dep_types,
                      const float* __restrict__ b1, const __hip_bfloat16* __restrict__ G1,
                      float* __restrict__ tok, float* __restrict__ tde) {
    int bi = blockIdx.x;  // b*128 + i
    int b = bi >> 7, i = bi & 127;
    int p = threadIdx.x;  // 128
    __shared__ int hs[128];
    __shared__ float row[128];
#pragma unroll 1
    for (int it = 0; it < AMP; it++) {
        int z = opaque_zero();
        hs[p] = heads[b * 128 + p + z];
        __syncthreads();
        float cbg = basics[p];
        float acc = basics[128 + p];  // base[p]
        for (int j = 0; j < 128; j++) {
            if (hs[j] == i) {          // block-uniform branch
                int gg = (b * 128 + j) * 128 + p;
                float s = 0.f;
#pragma unroll
                for (int k = 0; k < KSPLIT; k++) s += part[(size_t)k * NN * 128 + gg + z];
                float c = tanhf(s + b2[p]);
                acc += wr[j] * (c - cbg);
            }
        }
        tok[(size_t)bi * 128 + p] = acc;
        row[p] = acc;
        __syncthreads();
        int v = dep_types[bi];
        const unsigned* g = (const unsigned*)(G1 + (size_t)v * (TT * DD) + p * 128) + z;
        float a2 = b1[p];
#pragma unroll
        for (int ii = 0; ii < 16; ii++) {
            u32x4 w = *(const u32x4*)(g + ii * 4);
            a2 += row[ii * 8 + 0] * bflo(w[0]) + row[ii * 8 + 1] * bfhi(w[0]);
            a2 += row[ii * 8 + 2] * bflo(w[1]) + row[ii * 8 + 3] * bfhi(w[1]);
            a2 += row[ii * 8 + 4] * bflo(w[2]) + row[ii * 8 + 5] * bfhi(w[2]);
            a2 += row[ii * 8 + 6] * bflo(w[3]) + row[ii * 8 + 7] * bfhi(w[3]);
        }
        tde[(size_t)bi * 128 + p] = tanhf(a2);
        __syncthreads();
    }
}

// ---------------- e2b (final): root mask -> most blocks write zeros ----------------
__global__ void k_e2b(const float* __restrict__ part, const int* __restrict__ heads,
                      const float* __restrict__ basics, const float* __restrict__ wr,
                      const float* __restrict__ b2, float* __restrict__ out) {
    int bi = blockIdx.x;  // b*128 + i
    int b = bi >> 7, i = bi & 127;
    int p = threadIdx.x;  // 128
    __shared__ int hs[128];
#pragma unroll 1
    for (int it = 0; it < AMP; it++) {
        int z = opaque_zero();
        hs[p] = heads[b * 128 + p + z];
        __syncthreads();
        if (hs[i] != 0) {
            out[(size_t)bi * 128 + p] = 0.f;
        } else {
            float cbg = basics[p];
            float acc = basics[128 + p];
            for (int j = 0; j < 128; j++) {
                if (hs[j] == i) {
                    int gg = (b * 128 + j) * 128 + p;
                    float s = 0.f;
#pragma unroll
                    for (int k = 0; k < KSPLIT; k++) s += part[(size_t)k * NN * 128 + gg + z];
                    float c = tanhf(s + b2[p]);
                    acc += wr[j] * (c - cbg);
                }
            }
            out[(size_t)bi * 128 + p] = acc;
        }
        __syncthreads();
    }
}

extern "C" void kernel_launch(void* const* d_in, const int* in_sizes, int n_in,
                              void* d_out, int out_size, void* d_ws, size_t ws_size,
                              hipStream_t stream) {
    const float* token_table = (const float*)d_in[0];
    const float* dep_table   = (const float*)d_in[1];
    const float* W1          = (const float*)d_in[2];
    const float* b1          = (const float*)d_in[3];
    const float* W2          = (const float*)d_in[4];
    const float* b2          = (const float*)d_in[5];
    const float* wr          = (const float*)d_in[6];
    const float* br          = (const float*)d_in[7];
    const int* tokens        = (const int*)d_in[8];
    const int* dep_types     = (const int*)d_in[9];
    const int* dep_heads     = (const int*)d_in[10];
    float* out = (float*)d_out;

    char* ws = (char*)d_ws;
    __hip_bfloat16* G1  = (__hip_bfloat16*)(ws);                      // 2 MB
    __hip_bfloat16* W2b = (__hip_bfloat16*)(ws + (2ull << 20));       // 4 MB
    float* tok    = (float*)(ws + (6ull << 20));                      // 1 MB
    float* tde    = (float*)(ws + (7ull << 20));                      // 1 MB
    float* part   = (float*)(ws + (9ull << 20));                      // 16 MB
    float* basics = (float*)(ws + (25ull << 20));                     // 1 KB

    k_prep1<<<1537, 256, 0, stream>>>(W1, dep_table, W2, b2, wr, br, G1, W2b, basics);
    k_prep2<<<1024, 256, 0, stream>>>(token_table, tokens, dep_types, b1, G1, tok, tde);

    // depth 0
    k_gemm<<<dim3(32, KSPLIT), 256, 0, stream>>>(tok, tde, W2b, part);
    k_e2a<<<NN, 128, 0, stream>>>(part, dep_heads, basics, wr, b2,
                                  dep_types, b1, G1, tok, tde);
    // depth 1
    k_gemm<<<dim3(32, KSPLIT), 256, 0, stream>>>(tok, tde, W2b, part);
    k_e2b<<<NN, 128, 0, stream>>>(part, dep_heads, basics, wr, b2, out);
}

// Round 14
// 103.200 us; speedup vs baseline: 15.4369x; 15.4369x over previous
//
#include <hip/hip_runtime.h>
#include <hip/hip_bf16.h>

// Problem constants
#define BB 16
#define SS 128
#define DD 128
#define EE 64
#define TT 128
#define NN (BB*SS)      // 2048 tokens
#define KSPLIT 16       // K split for the big GEMM (d-chunks of 8)

typedef __attribute__((ext_vector_type(8))) short short8;
typedef __attribute__((ext_vector_type(4))) float f32x4;
typedef __attribute__((ext_vector_type(4))) unsigned int u32x4;

__device__ inline unsigned pkbf16(float a, float b) {
    unsigned r;
    asm volatile("v_cvt_pk_bf16_f32 %0, %1, %2" : "=v"(r) : "v"(a), "v"(b));
    return r;
}
__device__ inline float bflo(unsigned u) { return __builtin_bit_cast(float, (unsigned)(u << 16)); }
__device__ inline float bfhi(unsigned u) { return __builtin_bit_cast(float, (unsigned)(u & 0xffff0000u)); }

#define LDS_SWZ(row, bcol) ((row) * 256 + ((bcol) ^ (((row) & 7) << 4)))

// ---------------- prep1: g1 (512 blk) + w2b (1024) + basics (1) ----------------
__global__ __launch_bounds__(256) void k_prep1(const float* __restrict__ W1,
                                               const float* __restrict__ dep_table,
                                               const float* __restrict__ W2,
                                               const float* __restrict__ b2,
                                               const float* __restrict__ wr,
                                               const float* __restrict__ br,
                                               __hip_bfloat16* __restrict__ G1,
                                               __hip_bfloat16* __restrict__ W2b,
                                               float* __restrict__ basics) {
    int bid = blockIdx.x;
    int tid = threadIdx.x;
    if (bid < 512) {
        // --- G1[v][t][d] = sum_e W1[t][d][e]*dep_table[v][e] (bf16) ---
        int bx = bid & 63, by = bid >> 6;
        int td = bx * 256 + tid;  // t*128 + d
        int v0 = by * 8;          // 8 v per block
        const float* w1row = W1 + (size_t)td * 64;
        float acc[8] = {};
#pragma unroll
        for (int e0 = 0; e0 < 64; e0 += 8) {
            f32x4 wa = *(const f32x4*)(w1row + e0);
            f32x4 wb = *(const f32x4*)(w1row + e0 + 4);
#pragma unroll
            for (int v = 0; v < 8; v++) {
                const float* dr = dep_table + (v0 + v) * 64 + e0;  // wave-uniform -> s_load
                acc[v] += wa[0] * dr[0] + wa[1] * dr[1] + wa[2] * dr[2] + wa[3] * dr[3]
                        + wb[0] * dr[4] + wb[1] * dr[5] + wb[2] * dr[6] + wb[3] * dr[7];
            }
        }
#pragma unroll
        for (int v = 0; v < 8; v++)
            G1[(size_t)(v0 + v) * (TT * DD) + td] = __float2bfloat16(acc[v]);
    } else if (bid < 1536) {
        // --- W2b pre-swizzled bf16: per d, [p=128][256B row], slot s holds t-range (s^(p&7)) ---
        int cid = (bid - 512) * 256 + tid;  // 262144 chunks of 16B
        int d = cid >> 11;
        int rem = cid & 2047;
        int p = rem >> 4;
        int sp = rem & 15;
        int h = sp >> 3, s = sp & 7;
        int t0 = h * 64 + ((s ^ (p & 7))) * 8;
        const float* src = W2 + ((size_t)p * 128 + d) * 128 + t0;  // W2[p][d][t]
        f32x4 a = *(const f32x4*)(src);
        f32x4 b = *(const f32x4*)(src + 4);
        u32x4 o;
        o[0] = pkbf16(a[0], a[1]);
        o[1] = pkbf16(a[2], a[3]);
        o[2] = pkbf16(b[0], b[1]);
        o[3] = pkbf16(b[2], b[3]);
        *(u32x4*)((char*)W2b + (size_t)cid * 16) = o;
    } else {
        // --- basics: c_bg[p], base[p] ---
        __shared__ float red[128];
        int t = tid;
        if (t < 128) red[t] = wr[t];
        __syncthreads();
        for (int s = 64; s > 0; s >>= 1) {
            if (t < s) red[t] += red[t + s];
            __syncthreads();
        }
        if (t < 128) {
            float swr = red[0];
            float cbg = tanhf(b2[t]);
            basics[t] = cbg;                     // c_bg[p]
            basics[128 + t] = swr * cbg + br[0]; // base[p]
        }
    }
}

// ---------------- prep2: gather tok (2 rows/block) + fused depth-0 tde ----------------
__global__ __launch_bounds__(256) void k_prep2(const float* __restrict__ token_table,
                                               const int* __restrict__ tokens,
                                               const int* __restrict__ dep_types,
                                               const float* __restrict__ b1,
                                               const __hip_bfloat16* __restrict__ G1,
                                               float* __restrict__ tok,
                                               float* __restrict__ tde) {
    __shared__ float rows[2][128];
    int tid = threadIdx.x;
    int gid = blockIdx.x * 256 + tid;
    int n = gid >> 7, t = tid & 127, half = tid >> 7;
    float val = token_table[(size_t)tokens[n] * 128 + t];
    tok[gid] = val;
    rows[half][t] = val;
    __syncthreads();
    // tde[n][t] = tanh(b1[t] + sum_d rows[half][d]*G1[v][t][d])
    int v = dep_types[n];
    const unsigned* g = (const unsigned*)(G1 + (size_t)v * (TT * DD) + t * 128);
    const float* row = rows[half];
    float acc = b1[t];
#pragma unroll
    for (int i = 0; i < 16; i++) {
        u32x4 w = *(const u32x4*)(g + i * 4);
        acc += row[i * 8 + 0] * bflo(w[0]) + row[i * 8 + 1] * bfhi(w[0]);
        acc += row[i * 8 + 2] * bflo(w[1]) + row[i * 8 + 3] * bfhi(w[1]);
        acc += row[i * 8 + 4] * bflo(w[2]) + row[i * 8 + 5] * bfhi(w[2]);
        acc += row[i * 8 + 6] * bflo(w[3]) + row[i * 8 + 7] * bfhi(w[3]);
    }
    tde[(size_t)n * 128 + t] = tanhf(acc);
}

// ---------------- big GEMM v2 (round-13 diagnosis: latency-bound @ 23% occupancy):
// BM=32, grid 64x16=1024 (4 blocks/CU @ 40KB LDS), B staged via global_load_lds
// (W2b pre-swizzled -> linear copy = gll's required pattern), conflict-free A writes.
// Accumulation order (dd->kk) identical to v1 -> bitwise-identical part.
__global__ __launch_bounds__(256, 4) void k_gemm(const float* __restrict__ tok,
                                                 const float* __restrict__ tde,
                                                 const __hip_bfloat16* __restrict__ W2b,
                                                 float* __restrict__ part) {
    __shared__ char As[8192];   // A tile [n=32][k=128t] bf16, swizzled
    __shared__ char Bs[32768];  // B tile [p=128][k=128t] bf16, pre-swizzled (linear copy)
    int nb = blockIdx.x, ks = blockIdx.y;
    int tid = threadIdx.x;
    int lane = tid & 63, w = tid >> 6;   // wave w owns p-range w*32
    int n0 = nb * 32, d0 = ks * 8;
    int lrow = lane & 15, lk = lane >> 4;
    int r = tid >> 3, o = tid & 7;       // A staging: row r (32 rows), 16-t chunk o
    int wbase16 = (tid & 192) * 16;      // wave-uniform LDS base; HW adds lane*16

    f32x4 acc[2][2] = {};

    for (int dd = 0; dd < 8; dd++) {
        int d = d0 + dd;
        // stage B: async linear copy of the pre-swizzled 32KB panel
        const char* bsrc = (const char*)W2b + (size_t)d * 32768;
#pragma unroll
        for (int i = 0; i < 8; i++) {
            __builtin_amdgcn_global_load_lds(
                (const __attribute__((address_space(1))) void*)(bsrc + (i * 256 + tid) * 16),
                (__attribute__((address_space(3))) void*)(Bs + i * 4096 + wbase16),
                16, 0, 0);
        }
        // stage A: products tok[n][d]*tde[n][t], 16 t-values per thread (conflict-free)
        float tokv = tok[(size_t)(n0 + r) * 128 + d];
        const float* trow = tde + (size_t)(n0 + r) * 128 + o * 16;
        f32x4 xa = *(const f32x4*)(trow);
        f32x4 xb = *(const f32x4*)(trow + 4);
        f32x4 ya = *(const f32x4*)(trow + 8);
        f32x4 yb = *(const f32x4*)(trow + 12);
        u32x4 v0, v1;
        v0[0] = pkbf16(xa[0] * tokv, xa[1] * tokv);
        v0[1] = pkbf16(xa[2] * tokv, xa[3] * tokv);
        v0[2] = pkbf16(xb[0] * tokv, xb[1] * tokv);
        v0[3] = pkbf16(xb[2] * tokv, xb[3] * tokv);
        v1[0] = pkbf16(ya[0] * tokv, ya[1] * tokv);
        v1[1] = pkbf16(ya[2] * tokv, ya[3] * tokv);
        v1[2] = pkbf16(yb[0] * tokv, yb[1] * tokv);
        v1[3] = pkbf16(yb[2] * tokv, yb[3] * tokv);
        *(u32x4*)(As + LDS_SWZ(r, o * 32))      = v0;
        *(u32x4*)(As + LDS_SWZ(r, o * 32 + 16)) = v1;
        __syncthreads();   // drains gll (vmcnt) + A writes (lgkm)
        // MFMA over 4 k-slices of 32
#pragma unroll
        for (int kk = 0; kk < 4; kk++) {
            short8 aF[2], bF[2];
#pragma unroll
            for (int mi = 0; mi < 2; mi++)
                aF[mi] = *(const short8*)(As + LDS_SWZ(mi * 16 + lrow, kk * 64 + lk * 16));
#pragma unroll
            for (int pj = 0; pj < 2; pj++)
                bF[pj] = *(const short8*)(Bs + LDS_SWZ(w * 32 + pj * 16 + lrow, kk * 64 + lk * 16));
#pragma unroll
            for (int mi = 0; mi < 2; mi++)
#pragma unroll
                for (int pj = 0; pj < 2; pj++)
                    acc[mi][pj] = __builtin_amdgcn_mfma_f32_16x16x32_bf16(
                        aF[mi], bF[pj], acc[mi][pj], 0, 0, 0);
        }
        __syncthreads();
    }
    // write fp32 partials
    float* pout = part + (size_t)ks * NN * 128;
#pragma unroll
    for (int mi = 0; mi < 2; mi++)
#pragma unroll
        for (int pj = 0; pj < 2; pj++)
#pragma unroll
            for (int rr = 0; rr < 4; rr++) {
                int row = mi * 16 + (lane >> 4) * 4 + rr;
                int col = w * 32 + pj * 16 + (lane & 15);
                pout[(size_t)(n0 + row) * 128 + col] = acc[mi][pj][rr];
            }
}

// ---------------- e2a (depth 0): fused e1 + scatter + fused tde for depth 1 ----------------
__global__ void k_e2a(const float* __restrict__ part, const int* __restrict__ heads,
                      const float* __restrict__ basics, const float* __restrict__ wr,
                      const float* __restrict__ b2, const int* __restrict__ dep_types,
                      const float* __restrict__ b1, const __hip_bfloat16* __restrict__ G1,
                      float* __restrict__ tok, float* __restrict__ tde) {
    int bi = blockIdx.x;  // b*128 + i
    int b = bi >> 7, i = bi & 127;
    int p = threadIdx.x;  // 128
    __shared__ int hs[128];
    __shared__ float row[128];
    hs[p] = heads[b * 128 + p];
    __syncthreads();
    float cbg = basics[p];
    float acc = basics[128 + p];  // base[p]
    for (int j = 0; j < 128; j++) {
        if (hs[j] == i) {          // block-uniform branch
            int gg = (b * 128 + j) * 128 + p;
            float s = 0.f;
#pragma unroll
            for (int k = 0; k < KSPLIT; k++) s += part[(size_t)k * NN * 128 + gg];
            float c = tanhf(s + b2[p]);
            acc += wr[j] * (c - cbg);
        }
    }
    tok[(size_t)bi * 128 + p] = acc;
    row[p] = acc;
    __syncthreads();
    // tde row bi for the next depth (p doubles as t)
    int v = dep_types[bi];
    const unsigned* g = (const unsigned*)(G1 + (size_t)v * (TT * DD) + p * 128);
    float a2 = b1[p];
#pragma unroll
    for (int ii = 0; ii < 16; ii++) {
        u32x4 w = *(const u32x4*)(g + ii * 4);
        a2 += row[ii * 8 + 0] * bflo(w[0]) + row[ii * 8 + 1] * bfhi(w[0]);
        a2 += row[ii * 8 + 2] * bflo(w[1]) + row[ii * 8 + 3] * bfhi(w[1]);
        a2 += row[ii * 8 + 4] * bflo(w[2]) + row[ii * 8 + 5] * bfhi(w[2]);
        a2 += row[ii * 8 + 6] * bflo(w[3]) + row[ii * 8 + 7] * bfhi(w[3]);
    }
    tde[(size_t)bi * 128 + p] = tanhf(a2);
}

// ---------------- e2b (final): root mask first -> ~99% of blocks just write zeros ----------------
__global__ void k_e2b(const float* __restrict__ part, const int* __restrict__ heads,
                      const float* __restrict__ basics, const float* __restrict__ wr,
                      const float* __restrict__ b2, float* __restrict__ out) {
    int bi = blockIdx.x;  // b*128 + i
    int b = bi >> 7, i = bi & 127;
    int p = threadIdx.x;  // 128
    __shared__ int hs[128];
    hs[p] = heads[b * 128 + p];
    __syncthreads();
    if (hs[i] != 0) {              // masked row: zero and exit
        out[(size_t)bi * 128 + p] = 0.f;
        return;
    }
    float cbg = basics[p];
    float acc = basics[128 + p];
    for (int j = 0; j < 128; j++) {
        if (hs[j] == i) {
            int gg = (b * 128 + j) * 128 + p;
            float s = 0.f;
#pragma unroll
            for (int k = 0; k < KSPLIT; k++) s += part[(size_t)k * NN * 128 + gg];
            float c = tanhf(s + b2[p]);
            acc += wr[j] * (c - cbg);
        }
    }
    out[(size_t)bi * 128 + p] = acc;
}

extern "C" void kernel_launch(void* const* d_in, const int* in_sizes, int n_in,
                              void* d_out, int out_size, void* d_ws, size_t ws_size,
                              hipStream_t stream) {
    const float* token_table = (const float*)d_in[0];
    const float* dep_table   = (const float*)d_in[1];
    const float* W1          = (const float*)d_in[2];
    const float* b1          = (const float*)d_in[3];
    const float* W2          = (const float*)d_in[4];
    const float* b2          = (const float*)d_in[5];
    const float* wr          = (const float*)d_in[6];
    const float* br          = (const float*)d_in[7];
    const int* tokens        = (const int*)d_in[8];
    const int* dep_types     = (const int*)d_in[9];
    const int* dep_heads     = (const int*)d_in[10];
    float* out = (float*)d_out;

    char* ws = (char*)d_ws;
    __hip_bfloat16* G1  = (__hip_bfloat16*)(ws);                      // 2 MB
    __hip_bfloat16* W2b = (__hip_bfloat16*)(ws + (2ull << 20));       // 4 MB
    float* tok    = (float*)(ws + (6ull << 20));                      // 1 MB
    float* tde    = (float*)(ws + (7ull << 20));                      // 1 MB
    float* part   = (float*)(ws + (9ull << 20));                      // 16 MB
    float* basics = (float*)(ws + (25ull << 20));                     // 1 KB

    k_prep1<<<1537, 256, 0, stream>>>(W1, dep_table, W2, b2, wr, br, G1, W2b, basics);
    k_prep2<<<1024, 256, 0, stream>>>(token_table, tokens, dep_types, b1, G1, tok, tde);

    // depth 0
    k_gemm<<<dim3(64, KSPLIT), 256, 0, stream>>>(tok, tde, W2b, part);
    k_e2a<<<NN, 128, 0, stream>>>(part, dep_heads, basics, wr, b2,
                                  dep_types, b1, G1, tok, tde);
    // depth 1
    k_gemm<<<dim3(64, KSPLIT), 256, 0, stream>>>(tok, tde, W2b, part);
    k_e2b<<<NN, 128, 0, stream>>>(part, dep_heads, basics, wr, b2, out);
}